// Round 22
// baseline (118.911 us; speedup 1.0000x reference)
//
#include <hip/hip_runtime.h>

// Green-Ampt infiltration scan. B=16384 rows x T=2048 steps. Single pass,
// producer/consumer wave split + NONTEMPORAL flush stores, 2 blocks/CU.
// == FINAL: this is R18, the measured optimum (97.4us). ==
//
// Evidence ledger:
//  R1-R9:  cached-store regime pinned at ~3 TB/s (cache write path = wall:
//          write-allocate + partial-line set-thrash; concurrency/run-length/
//          bank-rotation/L2-set variants all null in that regime).
//  R10:    wave-contiguous (full-line) nontemporal stores -> 132us.
//  R11/R12: dedicated store waves 3 -> 6 (1 blk/CU): 120 -> 106us.
//  R13: 12 waves/blk 116us. R14: LDS-flag handshake 112.6us.
//  R16: 512B runs 111.9us. R15: 2-pass contiguous 215us.
//  R18: ROWS=32, 2 blocks/CU, 6 consumers (4KB/wave/stage) -> 97.4us. BEST.
//  R19: 4 blk/CU, 2KB/wave -> 233us.  R20: 2 blk/CU, 3 consumers -> 116.7us.
//  R21: 4 blk/CU, 12 waves x 4KB -> 116.5us.
// Optimum per CU: 2 async barrier chains x (1 producer + 6 store waves),
// 4KB/wave/stage nt stores. Combined HBM ~5.5 TB/s vs 6.3 TB/s ceiling;
// residual = serial-recurrence pipeline structure (produce->drain staging).

#define GA_MIN_INF 0.1f
#define GA_EPS 1e-6f

typedef float f4 __attribute__((ext_vector_type(4)));

constexpr int ROWS  = 32;   // rows per block
constexpr int TS    = 64;   // timesteps per stage (256B per row per stream)
constexpr int PITCH = 68;   // LDS row pitch in floats (16B-aligned)

__global__ __launch_bounds__(448, 1) void ga_pc(
    const float* __restrict__ precip, const float* __restrict__ K,
    const float* __restrict__ psi, const float* __restrict__ dtheta,
    float* __restrict__ out, int B, int T) {
  __shared__ float sb[2][3][ROWS * PITCH];   // 52.2 KB -> 2 blocks/CU

  const int tid  = threadIdx.x;
  const int wid  = tid >> 6;
  const int lane = tid & 63;
  const int rowbase = blockIdx.x * ROWS;

  const size_t BT = (size_t)B * (size_t)T;
  const int nstage = T / TS;                 // 32
  const int nsb    = T / 32;                 // 32-step sub-batches (64)

  if (wid == 0) {
    // ------------- producer: 32 active lanes, serial recurrence ------------
    const bool active = lane < ROWS;
    const int b = rowbase + (active ? lane : 0);   // clamped; idle lanes unused
    const float Kv  = K[b];
    const float kpd = Kv * (psi[b] * dtheta[b]);
    const f4* __restrict__ pr = reinterpret_cast<const f4*>(precip + (size_t)b * T);

    float F = 0.0f;
    f4 buf[8], nxt[8];
    if (active) {
#pragma unroll
      for (int i = 0; i < 8; ++i) buf[i] = pr[i];
    }

    int sbc = 0;
    for (int st = 0; st < nstage; ++st) {
      const int pb = st & 1;
      if (active) {
        float* const L0 = &sb[pb][0][lane * PITCH];
        float* const L1 = &sb[pb][1][lane * PITCH];
        float* const L2 = &sb[pb][2][lane * PITCH];
#pragma unroll
        for (int q = 0; q < 2; ++q) {        // 2 x 32 steps = TS
          if (sbc + 1 < nsb) {
#pragma unroll
            for (int i = 0; i < 8; ++i) nxt[i] = pr[(sbc + 1) * 8 + i];
          }
#pragma unroll
          for (int i = 0; i < 8; ++i) {
            const f4 p = buf[i];
            f4 a, r, c;
#pragma unroll
            for (int j = 0; j < 4; ++j) {
              float rF   = __builtin_amdgcn_rcpf(fmaxf(F, GA_EPS));
              float fcap = fmaxf(Kv + kpd * rF, GA_MIN_INF);
              float fact = fminf(p[j], fcap);
              r[j] = fmaxf(p[j] - fact, 0.0f);
              F += fact;
              a[j] = fact;
              c[j] = F;
            }
            const int t0 = q * 32 + i * 4;
            *reinterpret_cast<f4*>(L0 + t0) = a;
            *reinterpret_cast<f4*>(L1 + t0) = r;
            *reinterpret_cast<f4*>(L2 + t0) = c;
          }
#pragma unroll
          for (int i = 0; i < 8; ++i) buf[i] = nxt[i];
          ++sbc;
        }
      } else {
        sbc += 2;                             // keep loop-carried state uniform
      }
      // reconverged: one barrier per stage for the whole wave
      asm volatile("s_waitcnt lgkmcnt(0)" ::: "memory");
      __builtin_amdgcn_s_barrier();
    }
  } else {
    // ---------- consumers: 2 waves per stream (row halves), nt stores ------
    const int s = (wid - 1) % 3;             // stream
    const int h = (wid - 1) / 3;             // row half: rows h*16 .. h*16+15
    float* const dst = out + (size_t)s * BT;
    const int fr = lane >> 4;                // 0..3 : row within quad
    const int fc = (lane & 15) * 4;          // float col 0..60

    for (int st = 0; st < nstage; ++st) {
      if (st > 0) {
        const int tb = (st - 1) * TS;
        const float* const src = &sb[(st - 1) & 1][s][0];
#pragma unroll
        for (int g = 0; g < 4; ++g) {
          const int r = h * 16 + g * 4 + fr;
          f4 v = *reinterpret_cast<const f4*>(&src[r * PITCH + fc]);
          __builtin_nontemporal_store(
              v, reinterpret_cast<f4*>(dst + (size_t)(rowbase + r) * T + tb + fc));
        }
      }
      asm volatile("s_waitcnt lgkmcnt(0)" ::: "memory");
      __builtin_amdgcn_s_barrier();
    }
    // drain final stage (producer is done; no barrier needed)
    {
      const int tb = (nstage - 1) * TS;
      const float* const src = &sb[(nstage - 1) & 1][s][0];
#pragma unroll
      for (int g = 0; g < 4; ++g) {
        const int r = h * 16 + g * 4 + fr;
        f4 v = *reinterpret_cast<const f4*>(&src[r * PITCH + fc]);
        __builtin_nontemporal_store(
            v, reinterpret_cast<f4*>(dst + (size_t)(rowbase + r) * T + tb + fc));
      }
    }
  }
}

// Fallback for shapes not divisible by the tiling (not hit for 16384x2048).
__global__ void ga_fallback(
    const float* __restrict__ precip, const float* __restrict__ K,
    const float* __restrict__ psi, const float* __restrict__ dtheta,
    float* __restrict__ out, int B, int T) {
  int b = blockIdx.x * blockDim.x + threadIdx.x;
  if (b >= B) return;
  const float Kv  = K[b];
  const float kpd = Kv * (psi[b] * dtheta[b]);
  const size_t BT = (size_t)B * (size_t)T;
  float F = 0.0f;
  for (int t = 0; t < T; ++t) {
    float pv   = precip[(size_t)b * T + t];
    float rF   = __builtin_amdgcn_rcpf(fmaxf(F, GA_EPS));
    float fcap = fmaxf(Kv + kpd * rF, GA_MIN_INF);
    float fact = fminf(pv, fcap);
    float ro   = fmaxf(pv - fact, 0.0f);
    F += fact;
    out[(size_t)b * T + t] = fact;
    out[BT + (size_t)b * T + t] = ro;
    out[2 * BT + (size_t)b * T + t] = F;
  }
}

extern "C" void kernel_launch(void* const* d_in, const int* in_sizes, int n_in,
                              void* d_out, int out_size, void* d_ws, size_t ws_size,
                              hipStream_t stream) {
  const float* precip = (const float*)d_in[0];
  const float* K      = (const float*)d_in[1];
  const float* psi    = (const float*)d_in[2];
  const float* dtheta = (const float*)d_in[3];
  float* out = (float*)d_out;

  const int B = in_sizes[1];            // K has B elements
  const int T = in_sizes[0] / B;        // precip is B*T

  if ((B % ROWS) == 0 && (T % TS) == 0 && ((T / 32) % 2) == 0) {
    ga_pc<<<B / ROWS, 448, 0, stream>>>(precip, K, psi, dtheta, out, B, T);
  } else {
    ga_fallback<<<(B + 63) / 64, 64, 0, stream>>>(precip, K, psi, dtheta, out, B, T);
  }
}

// Round 23
// 96.518 us; speedup vs baseline: 1.2320x; 1.2320x over previous
//
#include <hip/hip_runtime.h>

// Green-Ampt infiltration scan. B=16384 rows x T=2048 steps. Single pass,
// producer/consumer wave split + NONTEMPORAL flush stores, 2 blocks/CU.
// == FINAL config (R18). R23 = variance check: identical binary, 3rd sample.
//
// Evidence ledger:
//  R1-R9:  cached-store regime pinned at ~3 TB/s (cache write path = wall:
//          write-allocate + partial-line set-thrash; concurrency/run-length/
//          bank-rotation/L2-set variants all null in that regime).
//  R10:    wave-contiguous (full-line) nontemporal stores -> 132us.
//  R11/R12: dedicated store waves 3 -> 6 (1 blk/CU): 120 -> 106us.
//  R18: ROWS=32, 2 blocks/CU, 6 consumers (4KB/wave/stage) -> 97.4us.
//  R19-R21: neighboring structural configs -> 116-233us.
//  R22: BYTE-IDENTICAL to R18 -> 118.9us. Run-to-run spread ~20% on the
//       same binary => R12..R21 fine-grained ranking was noise; real signal
//       is cached(176) -> nt(132) -> producer/consumer-nt(~97-119).
// R23: re-run identical kernel for a third sample to pin the honest number.

#define GA_MIN_INF 0.1f
#define GA_EPS 1e-6f

typedef float f4 __attribute__((ext_vector_type(4)));

constexpr int ROWS  = 32;   // rows per block
constexpr int TS    = 64;   // timesteps per stage (256B per row per stream)
constexpr int PITCH = 68;   // LDS row pitch in floats (16B-aligned)

__global__ __launch_bounds__(448, 1) void ga_pc(
    const float* __restrict__ precip, const float* __restrict__ K,
    const float* __restrict__ psi, const float* __restrict__ dtheta,
    float* __restrict__ out, int B, int T) {
  __shared__ float sb[2][3][ROWS * PITCH];   // 52.2 KB -> 2 blocks/CU

  const int tid  = threadIdx.x;
  const int wid  = tid >> 6;
  const int lane = tid & 63;
  const int rowbase = blockIdx.x * ROWS;

  const size_t BT = (size_t)B * (size_t)T;
  const int nstage = T / TS;                 // 32
  const int nsb    = T / 32;                 // 32-step sub-batches (64)

  if (wid == 0) {
    // ------------- producer: 32 active lanes, serial recurrence ------------
    const bool active = lane < ROWS;
    const int b = rowbase + (active ? lane : 0);   // clamped; idle lanes unused
    const float Kv  = K[b];
    const float kpd = Kv * (psi[b] * dtheta[b]);
    const f4* __restrict__ pr = reinterpret_cast<const f4*>(precip + (size_t)b * T);

    float F = 0.0f;
    f4 buf[8], nxt[8];
    if (active) {
#pragma unroll
      for (int i = 0; i < 8; ++i) buf[i] = pr[i];
    }

    int sbc = 0;
    for (int st = 0; st < nstage; ++st) {
      const int pb = st & 1;
      if (active) {
        float* const L0 = &sb[pb][0][lane * PITCH];
        float* const L1 = &sb[pb][1][lane * PITCH];
        float* const L2 = &sb[pb][2][lane * PITCH];
#pragma unroll
        for (int q = 0; q < 2; ++q) {        // 2 x 32 steps = TS
          if (sbc + 1 < nsb) {
#pragma unroll
            for (int i = 0; i < 8; ++i) nxt[i] = pr[(sbc + 1) * 8 + i];
          }
#pragma unroll
          for (int i = 0; i < 8; ++i) {
            const f4 p = buf[i];
            f4 a, r, c;
#pragma unroll
            for (int j = 0; j < 4; ++j) {
              float rF   = __builtin_amdgcn_rcpf(fmaxf(F, GA_EPS));
              float fcap = fmaxf(Kv + kpd * rF, GA_MIN_INF);
              float fact = fminf(p[j], fcap);
              r[j] = fmaxf(p[j] - fact, 0.0f);
              F += fact;
              a[j] = fact;
              c[j] = F;
            }
            const int t0 = q * 32 + i * 4;
            *reinterpret_cast<f4*>(L0 + t0) = a;
            *reinterpret_cast<f4*>(L1 + t0) = r;
            *reinterpret_cast<f4*>(L2 + t0) = c;
          }
#pragma unroll
          for (int i = 0; i < 8; ++i) buf[i] = nxt[i];
          ++sbc;
        }
      } else {
        sbc += 2;                             // keep loop-carried state uniform
      }
      // reconverged: one barrier per stage for the whole wave
      asm volatile("s_waitcnt lgkmcnt(0)" ::: "memory");
      __builtin_amdgcn_s_barrier();
    }
  } else {
    // ---------- consumers: 2 waves per stream (row halves), nt stores ------
    const int s = (wid - 1) % 3;             // stream
    const int h = (wid - 1) / 3;             // row half: rows h*16 .. h*16+15
    float* const dst = out + (size_t)s * BT;
    const int fr = lane >> 4;                // 0..3 : row within quad
    const int fc = (lane & 15) * 4;          // float col 0..60

    for (int st = 0; st < nstage; ++st) {
      if (st > 0) {
        const int tb = (st - 1) * TS;
        const float* const src = &sb[(st - 1) & 1][s][0];
#pragma unroll
        for (int g = 0; g < 4; ++g) {
          const int r = h * 16 + g * 4 + fr;
          f4 v = *reinterpret_cast<const f4*>(&src[r * PITCH + fc]);
          __builtin_nontemporal_store(
              v, reinterpret_cast<f4*>(dst + (size_t)(rowbase + r) * T + tb + fc));
        }
      }
      asm volatile("s_waitcnt lgkmcnt(0)" ::: "memory");
      __builtin_amdgcn_s_barrier();
    }
    // drain final stage (producer is done; no barrier needed)
    {
      const int tb = (nstage - 1) * TS;
      const float* const src = &sb[(nstage - 1) & 1][s][0];
#pragma unroll
      for (int g = 0; g < 4; ++g) {
        const int r = h * 16 + g * 4 + fr;
        f4 v = *reinterpret_cast<const f4*>(&src[r * PITCH + fc]);
        __builtin_nontemporal_store(
            v, reinterpret_cast<f4*>(dst + (size_t)(rowbase + r) * T + tb + fc));
      }
    }
  }
}

// Fallback for shapes not divisible by the tiling (not hit for 16384x2048).
__global__ void ga_fallback(
    const float* __restrict__ precip, const float* __restrict__ K,
    const float* __restrict__ psi, const float* __restrict__ dtheta,
    float* __restrict__ out, int B, int T) {
  int b = blockIdx.x * blockDim.x + threadIdx.x;
  if (b >= B) return;
  const float Kv  = K[b];
  const float kpd = Kv * (psi[b] * dtheta[b]);
  const size_t BT = (size_t)B * (size_t)T;
  float F = 0.0f;
  for (int t = 0; t < T; ++t) {
    float pv   = precip[(size_t)b * T + t];
    float rF   = __builtin_amdgcn_rcpf(fmaxf(F, GA_EPS));
    float fcap = fmaxf(Kv + kpd * rF, GA_MIN_INF);
    float fact = fminf(pv, fcap);
    float ro   = fmaxf(pv - fact, 0.0f);
    F += fact;
    out[(size_t)b * T + t] = fact;
    out[BT + (size_t)b * T + t] = ro;
    out[2 * BT + (size_t)b * T + t] = F;
  }
}

extern "C" void kernel_launch(void* const* d_in, const int* in_sizes, int n_in,
                              void* d_out, int out_size, void* d_ws, size_t ws_size,
                              hipStream_t stream) {
  const float* precip = (const float*)d_in[0];
  const float* K      = (const float*)d_in[1];
  const float* psi    = (const float*)d_in[2];
  const float* dtheta = (const float*)d_in[3];
  float* out = (float*)d_out;

  const int B = in_sizes[1];            // K has B elements
  const int T = in_sizes[0] / B;        // precip is B*T

  if ((B % ROWS) == 0 && (T % TS) == 0 && ((T / 32) % 2) == 0) {
    ga_pc<<<B / ROWS, 448, 0, stream>>>(precip, K, psi, dtheta, out, B, T);
  } else {
    ga_fallback<<<(B + 63) / 64, 64, 0, stream>>>(precip, K, psi, dtheta, out, B, T);
  }
}